// Round 8
// baseline (59.154 us; speedup 1.0000x reference)
//
#include <hip/hip_runtime.h>

#define NB 8
#define NL 512
#define ND 128

constexpr float CEXP = 2.8853900817779268f;   // 2*log2(e): exp2(CEXP*x) = e^{2x}

typedef float v2f __attribute__((ext_vector_type(2)));

// wpack: transpose+d4-pack weights (wp[(d>>2)*512 + e*4 + (d&3)] = w[e][d])
// so qk's weight loads are lane-coalesced.
__global__ __launch_bounds__(256) void wpack_kernel(
    const float* __restrict__ uw, const float* __restrict__ vw,
    float* __restrict__ uwp, float* __restrict__ vwp) {
  const int m = blockIdx.x >> 4;                        // 0: uw, 1: vw
  const int t = (blockIdx.x & 15) * 256 + threadIdx.x;  // 0..4095
  const float4* src = (const float4*)(m ? vw : uw);
  float4* dst = (float4*)(m ? vwp : uwp);
  const int e = t >> 5, d4 = t & 31;
  float4 v = src[e * 32 + d4];       // w[e][4d4..+3], coalesced read
  dst[d4 * 128 + e] = v;             // wp[d4][e][4]
}

// Kernel A: q = inp @ uw^T, k = inp @ vw^T.
//  eqp = exp2(CEXP*q), d4-packed-transposed [b][e4][l][4]  (VMEM stream)
//  ekq = exp2(CEXP*k), slot-interleaved [b][tile][e][8] with slot order
//        (i0,i4,i1,i5,i2,i6,i3,i7).
// inp rows are read via uniform s_loads (no LDS staging, no barrier).
__global__ __launch_bounds__(256) void qk_kernel(
    const float* __restrict__ inp, const float* __restrict__ uwp,
    const float* __restrict__ vwp, float* __restrict__ eqp,
    float* __restrict__ ekq) {
  __shared__ float qt[128][9];    // pad 9: conflict-free transpose
  const int b = blockIdx.x & 7;   // batch-per-XCD affinity (matches attn)
  const int l0 = (blockIdx.x >> 3) * 8;
  const int tid = threadIdx.x;

  const int e = tid & 127;
  const int half = tid >> 7;                 // 0 -> q (uw), 1 -> k (vw)
  const float* xrow = inp + (b * NL + l0) * ND;   // uniform base -> s_load
  const float4* W4 = (const float4*)(half ? vwp : uwp) + e;  // coalesced
  float acc[8];
#pragma unroll
  for (int r = 0; r < 8; ++r) acc[r] = 0.f;
  float4 w = W4[0];
  for (int d4 = 0; d4 < 32; ++d4) {
    float4 wn = W4[(size_t)((d4 + 1 > 31) ? 31 : d4 + 1) * 128];
#pragma unroll
    for (int r = 0; r < 8; ++r) {
      // uniform address -> scalar loads, broadcast as SGPR operands
      float4 x = *((const float4*)&xrow[r * ND + 4 * d4]);
      acc[r] = fmaf(w.x, x.x, acc[r]);
      acc[r] = fmaf(w.y, x.y, acc[r]);
      acc[r] = fmaf(w.z, x.z, acc[r]);
      acc[r] = fmaf(w.w, x.w, acc[r]);
    }
    w = wn;
  }
  if (half) {
    float* ekb = ekq + ((size_t)(b * 64 + (l0 >> 3)) * 128 + e) * 8;
#pragma unroll
    for (int r = 0; r < 8; ++r) {
      const int slot = (r & 3) * 2 + (r >> 2);
      ekb[slot] = __builtin_amdgcn_exp2f(CEXP * acc[r]);  // 32B/thread
    }
  } else {
#pragma unroll
    for (int r = 0; r < 8; ++r)
      qt[e][r] = __builtin_amdgcn_exp2f(CEXP * acc[r]);
  }
  __syncthreads();
  {
    // all 256 threads: thread -> (e4 = tid>>3, r = tid&7)
    const int e4 = tid >> 3, r = tid & 7;
    float4 v = make_float4(qt[4 * e4][r], qt[4 * e4 + 1][r],
                           qt[4 * e4 + 2][r], qt[4 * e4 + 3][r]);
    ((float4*)eqp)[(b * 32 + e4) * NL + l0 + r] = v;
  }
}

// Kernel B: 8-row i-tile, 512 threads, 512 blocks — round-0 structure
// (the 39.3us best) with ONE change: the score math is DE-PACKED from
// v_pk_*_f32 (VOPP) to scalar v_fma/v_mul, with empty asm "+v" barriers
// to stop SLP re-packing. WHY: across 7 variants (occupancy 2/4/8
// waves/SIMD, ek via K$ vs LDS, eq prefetch depth, broadcast volume
// halved) VALUBusy is pinned at 52-53% and dur*busy is conserved — the
// only invariant is the ~90%-VOPP instruction mix. Packed f32 reads 6
// dword operands; if RF-port/issue limits cap back-to-back VOPP issue
// at ~50%, scalar ops (m80 shows 86% VALUBusy is reachable on gfx950;
// m07 scalar-FMA hit 65% of peak) trade +8% issued cycles for a
// 1.2-1.6x higher sustain rate.
__global__ __launch_bounds__(512, 4) void attn_kernel(
    const float* __restrict__ inp, const float* __restrict__ aw,
    const float* __restrict__ eqp, const float* __restrict__ ekq,
    float* __restrict__ out, float* __restrict__ attn) {
  __shared__ v2f red[8][8][64];        // PV partials (32KB)
  __shared__ float attn_lds[8][512];   // 16KB
  __shared__ float rsum[8][8];

  const int b = blockIdx.x & 7;       // batch-per-XCD affinity
  const int i0 = (blockIdx.x >> 3) * 8;
  const int tid = threadIdx.x;
  const int lane = tid & 63;
  const int wid = tid >> 6;

  // ---- score stage: thread owns column j = tid; 8 scalar row-accs
  float ac0 = 0.f, ac1 = 0.f, ac2 = 0.f, ac3 = 0.f;
  float ac4 = 0.f, ac5 = 0.f, ac6 = 0.f, ac7 = 0.f;
  const float4* eq4 = (const float4*)eqp + (size_t)(b * 32) * NL + tid;
  const float4* aw4 = (const float4*)aw;
  // uniform pointer; per d two float4: slots {r0,r4,r1,r5} and {r2,r6,r3,r7}
  const float4* ekq4 =
      (const float4*)(ekq + (size_t)(b * 64 + (i0 >> 3)) * 128 * 8);
  float4 eA = eq4[0];
  float4 eB = eq4[NL];
#pragma unroll 4
  for (int d4 = 0; d4 < 32; ++d4) {
    const int nf = (d4 + 2 > 31) ? 31 : d4 + 2;      // 2-deep prefetch
    float4 eC = eq4[(size_t)nf * NL];
    float4 na4 = aw4[d4];                            // uniform -> s_load
#pragma unroll
    for (int dd = 0; dd < 4; ++dd) {
      const int d = 4 * d4 + dd;
      const float eqs = (dd == 0) ? eA.x : (dd == 1) ? eA.y
                       : (dd == 2) ? eA.z : eA.w;
      const float na = (dd == 0) ? na4.x : (dd == 1) ? na4.y
                      : (dd == 2) ? na4.z : na4.w;
      float4 k0 = ekq4[d * 2 + 0];   // uniform -> s_load_dwordx4
      float4 k1 = ekq4[d * 2 + 1];
      // p = 1 + eq*ek; tanh = 1 - 2/p; "+1" terms softmax-invariant,
      // the -2 is folded into the exp2 constant below.
      float P0 = fmaf(eqs, k0.x, 1.f);
      float P4 = fmaf(eqs, k0.y, 1.f);
      float P1 = fmaf(eqs, k0.z, 1.f);
      float P5 = fmaf(eqs, k0.w, 1.f);
      float P2 = fmaf(eqs, k1.x, 1.f);
      float P6 = fmaf(eqs, k1.y, 1.f);
      float P3 = fmaf(eqs, k1.z, 1.f);
      float P7 = fmaf(eqs, k1.w, 1.f);
      asm("" : "+v"(P0), "+v"(P1), "+v"(P2), "+v"(P3),
               "+v"(P4), "+v"(P5), "+v"(P6), "+v"(P7));   // SLP fence
      float M01 = P0 * P1, M23 = P2 * P3;
      float M45 = P4 * P5, M67 = P6 * P7;
      asm("" : "+v"(M01), "+v"(M23), "+v"(M45), "+v"(M67));
      float Qa = M01 * M23, Qb = M45 * M67;
      float Ta = na * __builtin_amdgcn_rcpf(Qa);   // na/p0123
      float Tb = na * __builtin_amdgcn_rcpf(Qb);   // na/p4567
      float T01 = Ta * M23, T23 = Ta * M01;        // na/p01, na/p23
      float T45 = Tb * M67, T67 = Tb * M45;        // na/p45, na/p67
      asm("" : "+v"(T01), "+v"(T23), "+v"(T45), "+v"(T67));
      ac0 = fmaf(T01, P1, ac0);
      ac1 = fmaf(T01, P0, ac1);
      ac2 = fmaf(T23, P3, ac2);
      ac3 = fmaf(T23, P2, ac3);
      ac4 = fmaf(T45, P5, ac4);
      ac5 = fmaf(T45, P4, ac5);
      ac6 = fmaf(T67, P7, ac6);
      ac7 = fmaf(T67, P6, ac7);
    }
    eA = eB;
    eB = eC;
  }
  float acc[8] = {ac0, ac1, ac2, ac3, ac4, ac5, ac6, ac7};

  // ---- softmax over j; score = -2*acc (fold -2 into exp2 constant);
  // no max-subtraction: |exp2 arg| <= ~26, safe in f32.
  float sinv[8], ex[8];
#pragma unroll
  for (int i = 0; i < 8; ++i) {
    float e = __builtin_amdgcn_exp2f(acc[i] * (-CEXP));
    ex[i] = e;
    float s = e;
#pragma unroll
    for (int off = 32; off; off >>= 1) s += __shfl_xor(s, off);
    if (lane == 0) rsum[wid][i] = s;
  }
  __syncthreads();
#pragma unroll
  for (int i = 0; i < 8; ++i) {
    float s = ((rsum[0][i] + rsum[1][i]) + (rsum[2][i] + rsum[3][i])) +
              ((rsum[4][i] + rsum[5][i]) + (rsum[6][i] + rsum[7][i]));
    sinv[i] = __builtin_amdgcn_rcpf(s);
  }

  float* attnb = attn + (size_t)(b * NL + i0) * NL;
#pragma unroll
  for (int i = 0; i < 8; ++i) {
    float a = ex[i] * sinv[i];
    attn_lds[i][tid] = a;
    attnb[i * NL + tid] = a;           // coalesced
  }
  __syncthreads();

  // ---- PV: wave w owns j in [64w, 64w+64); lane owns v2f d-pair
  v2f po[8];
#pragma unroll
  for (int i = 0; i < 8; ++i) po[i] = (v2f){0.f, 0.f};
  const v2f* inp2 = (const v2f*)(inp + b * NL * ND);
  for (int jj4 = 0; jj4 < 16; ++jj4) {
    const int jc = wid * 64 + jj4 * 4;
    v2f x0 = inp2[(jc + 0) * 64 + lane];   // coalesced (L2-resident)
    v2f x1 = inp2[(jc + 1) * 64 + lane];
    v2f x2 = inp2[(jc + 2) * 64 + lane];
    v2f x3 = inp2[(jc + 3) * 64 + lane];
#pragma unroll
    for (int i = 0; i < 8; ++i) {
      float4 a4 = *((const float4*)&attn_lds[i][jc]);   // uniform broadcast
      po[i] = __builtin_elementwise_fma((v2f){a4.x, a4.x}, x0, po[i]);
      po[i] = __builtin_elementwise_fma((v2f){a4.y, a4.y}, x1, po[i]);
      po[i] = __builtin_elementwise_fma((v2f){a4.z, a4.z}, x2, po[i]);
      po[i] = __builtin_elementwise_fma((v2f){a4.w, a4.w}, x3, po[i]);
    }
  }
#pragma unroll
  for (int i = 0; i < 8; ++i) red[wid][i][lane] = po[i];
  __syncthreads();
  {
    const int i2 = wid, dl = lane;
    v2f s = red[0][i2][dl];
#pragma unroll
    for (int p = 1; p < 8; ++p) s += red[p][i2][dl];
    *(v2f*)&out[(size_t)(b * NL + i0 + i2) * ND + dl * 2] = s;
  }
}

extern "C" void kernel_launch(void* const* d_in, const int* in_sizes, int n_in,
                              void* d_out, int out_size, void* d_ws,
                              size_t ws_size, hipStream_t stream) {
  const float* inp = (const float*)d_in[0];
  const float* uw = (const float*)d_in[1];
  const float* vw = (const float*)d_in[2];
  const float* aw = (const float*)d_in[3];
  float* out = (float*)d_out;
  float* attn = out + NB * NL * ND;        // tuple order: (out, attn)
  float* eqp = (float*)d_ws;               // [B][32][512][4] packed exp2 q
  float* ekq = eqp + NB * ND * NL;         // [B][64][128][8] slot-interleaved
  size_t need = (size_t)2 * NB * ND * NL * 4 + 32768 * 4;
  float* wp = (ws_size >= need) ? (ekq + NB * ND * NL) : (attn);
  float* uwp = wp;                 // 16384
  float* vwp = wp + 16384;         // 16384
  wpack_kernel<<<dim3(32), 256, 0, stream>>>(uw, vw, uwp, vwp);
  qk_kernel<<<dim3(NB * 64), 256, 0, stream>>>(inp, uwp, vwp, eqp, ekq);
  attn_kernel<<<dim3(NB * 64), 512, 0, stream>>>(inp, aw, eqp, ekq, out, attn);
}